// Round 10
// baseline (90.546 us; speedup 1.0000x reference)
//
#include <hip/hip_runtime.h>

// TripletLoss, N=384, D=512, fp32 in, int labels, fp32 scalar out.
// loss = sum_a sum_p sum_n relu(d(a,p)-d(a,n)+1) / num_valid (diag counts as pos)
//
// R16 post-mortem: MFMA Gram engine cut 79.6 -> 70.8us (absmax 0.0). Budget:
// 40us fill (256MiB cache-scrub, fixed) + ~30us kernels+boundaries. Next
// lever: kill the K1->K2 dispatch boundary. Cooperative launch silently fails
// here (R7) and a ticket counter needs zeroed ws (poisoned every iter), so:
// per-block MAGIC flags. 96 flag cells in ws; block b atomicExch's a multi-
// byte MAGIC (can't collide with a repeated-byte fill pattern) after
// threadfence; everyone polls all 96 cells with a BOUNDED spin (escape ->
// absmax fail, never a hang). 96 blocks <= 256 CUs -> all co-resident at
// launch -> no dispatch deadlock.
//
// Phase 1: 32x48 C-tiles (12x8 grid, 6 waves = 2x3 16x16 MFMA subtiles),
// 80 rows staged as bf16 in LDS (R16's verified swizzle/fragment/epilogue,
// re-parameterized). Phase 2: block b handles anchors 4b..4b+3 with the
// R14-proven 384-thread compaction + R12-proven g-loop barriers; one
// atomicAdd(out, bs/nv) per block (out zeroed by harness each launch).

#define NPTS 384
#define DIM  512
#define NT   384
#define NW   (NT / 64)     // 6 waves
#define NBI  12            // 32-row A panels
#define NBJ  8             // 48-col B panels
#define NB   (NBI * NBJ)   // 96 blocks
#define APB  4             // anchors per block in phase 2
#define MAGIC 0x7FA1B2C3u  // bytes all distinct -> != any repeated-byte poison
#define FLAG_STRIDE 16     // u32 stride between flag cells (64B apart)

typedef __attribute__((ext_vector_type(8))) short bf16x8;
typedef __attribute__((ext_vector_type(4))) float f32x4;

__device__ __forceinline__ ushort f2bf(float f) {     // RNE f32 -> bf16
    uint u = __float_as_uint(f);
    u += 0x7fffu + ((u >> 16) & 1u);
    return (ushort)(u >> 16);
}

__global__ __launch_bounds__(NT) void triplet_one(
    const float* __restrict__ X,
    const int*   __restrict__ labels,
    float*       __restrict__ D,       // ws: 384*384*4 B
    unsigned*    __restrict__ flags,   // ws + 589824: 96 cells, stride 16 u32
    float*       __restrict__ out)
{
    __shared__ ushort s_T[80 * 512] __attribute__((aligned(16)));  // 80 KB
    __shared__ float  s_nrmp[4][80];
    __shared__ float  s_dp[NPTS];
    __shared__ float  s_dn[NPTS];
    __shared__ int    s_lab[NPTS] __attribute__((aligned(16)));
    __shared__ int    s_cp[NW], s_cn[NW];
    __shared__ float  s_red[NW];
    __shared__ int    s_nv[NW];

    const int t    = threadIdx.x;
    const int lane = t & 63, w = t >> 6;
    const int b    = blockIdx.x;
    const int bi   = (b >> 3) * 32;        // A panel: 32 rows
    const int bj   = (b & 7)  * 48;        // B panel: 48 rows (C cols)

    const float4* X4 = (const float4*)X;   // row pitch DIM/4 = 128

    // ---- phase 1a: stage 80 rows (32 A + 48 B) as swizzled bf16 ------------
#pragma unroll
    for (int p = 0; p < 27; ++p) {
        const int idx = p * NT + t;        // 0..10239 used
        if (idx < 80 * 128) {
            const int row  = idx >> 7;     // LDS row 0..79
            const int col4 = idx & 127;
            const int grow = (row < 32) ? (bi + row) : (bj + row - 32);
            const float4 v = X4[(size_t)grow * 128 + col4];
            const uint lo = (uint)f2bf(v.x) | ((uint)f2bf(v.y) << 16);
            const uint hi = (uint)f2bf(v.z) | ((uint)f2bf(v.w) << 16);
            const int off = (col4 * 8) ^ ((row & 7) << 4);   // 16B-grain XOR
            *(uint2*)((char*)s_T + row * 1024 + off) = make_uint2(lo, hi);
        }
    }
    s_lab[t] = labels[t];
    __syncthreads();

    // ---- phase 1b: norms from staged bf16 (waves 0..4, 16 rows each) -------
    if (w < 5) {
        const int row = w * 16 + (lane & 15);    // 0..79
        const int q   = lane >> 4;               // k-quarter
        const char* src = (const char*)s_T + row * 1024;
        float nrm = 0.f;
#pragma unroll
        for (int c = 0; c < 16; ++c) {
            const int cb = q * 256 + c * 16;
            const bf16x8 hv = *(const bf16x8*)(src + (cb ^ ((row & 7) << 4)));
#pragma unroll
            for (int j = 0; j < 8; ++j) {
                const float f = __uint_as_float(((uint)(ushort)hv[j]) << 16);
                nrm = fmaf(f, f, nrm);
            }
        }
        s_nrmp[q][row] = nrm;
    }

    // ---- phase 1c: Gram via mfma_f32_16x16x32_bf16 (2x3 wave grid) ---------
    f32x4 acc = {0.f, 0.f, 0.f, 0.f};
    const int wr  = w / 3, wc = w % 3;
    const int ar  = wr * 16 + (lane & 15);       // A local row
    const int brl = 32 + wc * 16 + (lane & 15);  // B local row in s_T
    const char* pa = (const char*)s_T + ar  * 1024;
    const char* pb = (const char*)s_T + brl * 1024;
    const int kg = (lane >> 4) * 16;
#pragma unroll
    for (int kt = 0; kt < 16; ++kt) {
        const int kb = kt * 64 + kg;
        const bf16x8 af = *(const bf16x8*)(pa + (kb ^ ((ar  & 7) << 4)));
        const bf16x8 bv = *(const bf16x8*)(pb + (kb ^ ((brl & 7) << 4)));
        acc = __builtin_amdgcn_mfma_f32_16x16x32_bf16(af, bv, acc, 0, 0, 0);
    }
    __syncthreads();                             // s_nrmp complete

    // ---- phase 1d: d = sqrt(max(nA+nB-2G, 0)); diag forced 0 ---------------
    {
        const int bcol = wc * 16 + (lane & 15);
        const float nB = s_nrmp[0][32 + bcol] + s_nrmp[1][32 + bcol] +
                         s_nrmp[2][32 + bcol] + s_nrmp[3][32 + bcol];
#pragma unroll
        for (int v = 0; v < 4; ++v) {
            const int il = wr * 16 + (lane >> 4) * 4 + v;
            const float nA = s_nrmp[0][il] + s_nrmp[1][il] +
                             s_nrmp[2][il] + s_nrmp[3][il];
            const float d2 = nA + nB - 2.f * acc[v];
            const int gi = bi + il, gj = bj + bcol;
            D[(size_t)gi * NPTS + gj] = (gi == gj) ? 0.f
                                                   : sqrtf(fmaxf(d2, 0.f));
        }
    }

    // ---- device barrier: flag + bounded poll (init-free, hang-free) --------
    __threadfence();                             // flush this thread's D writes
    __syncthreads();                             // whole block's writes issued
    if (t == 0) atomicExch(&flags[b * FLAG_STRIDE], MAGIC);
    if (t < NB) {
        int spins = 0;
        while (atomicAdd(&flags[t * FLAG_STRIDE], 0u) != MAGIC &&
               ++spins < (1 << 20)) { }
    }
    __syncthreads();
    __threadfence();                             // acquire before reading D

    // ---- phase 2: 4 anchors/block, proven compaction + pair sum ------------
    const unsigned long long blw = (1ull << lane) - 1ull;   // lane<64, safe
    float local = 0.f;
#pragma unroll 1
    for (int g = 0; g < APB; ++g) {
        const int a     = b * APB + g;
        const int lab_a = s_lab[a];
        const float dv  = D[(size_t)a * NPTS + t];
        const bool  isp = (s_lab[t] == lab_a);   // diag j==a counts as pos
        const unsigned long long m = __ballot(isp);
        __syncthreads();                         // prev-g s_dp/s_dn reads done
        if (lane == 0) { s_cp[w] = __popcll(m); s_cn[w] = 64 - __popcll(m); }
        __syncthreads();

        int basep = 0, basen = 0, np = 0, nn = 0;
#pragma unroll
        for (int i = 0; i < NW; ++i) {
            if (i < w) { basep += s_cp[i]; basen += s_cn[i]; }
            np += s_cp[i]; nn += s_cn[i];
        }
        if (isp) s_dp[basep + __popcll(m  & blw)] = dv;
        else     s_dn[basen + __popcll(~m & blw)] = dv;
        __syncthreads();

        const bool  va  = (t < nn);
        const float dna = va ? s_dn[t] : 0.f;
        for (int p = 0; p < np; ++p) {
            const float c = s_dp[p] + 1.0f;      // MARGIN
            if (va) local += fmaxf(c - dna, 0.f);
        }
    }

    // ---- global num_valid from labels alone (identical in every block) -----
    const int myl = s_lab[t];
    int npt = 0;
    const int4* L4 = (const int4*)s_lab;
#pragma unroll 8
    for (int j4 = 0; j4 < NPTS / 4; ++j4) {
        const int4 l = L4[j4];                   // broadcast read
        npt += (l.x == myl) + (l.y == myl) + (l.z == myl) + (l.w == myl);
    }
    int nvl = npt * (NPTS - npt);

    // ---- block reduce + atomic finish --------------------------------------
    for (int off = 32; off; off >>= 1) {
        local += __shfl_down(local, off, 64);
        nvl   += __shfl_down(nvl,   off, 64);
    }
    if (lane == 0) { s_red[w] = local; s_nv[w] = nvl; }
    __syncthreads();
    if (t == 0) {
        float bs = 0.f; int nv = 0;
#pragma unroll
        for (int i = 0; i < NW; ++i) { bs += s_red[i]; nv += s_nv[i]; }
        // out is memset to 0 by the harness before each verified launch
        atomicAdd(out, (float)((double)bs / ((double)nv + 1e-16)));
    }
}

extern "C" void kernel_launch(void* const* d_in, const int* in_sizes, int n_in,
                              void* d_out, int out_size, void* d_ws, size_t ws_size,
                              hipStream_t stream) {
    (void)in_sizes; (void)n_in; (void)out_size; (void)ws_size;
    const float* X      = (const float*)d_in[0];
    const int*   labels = (const int*)d_in[1];

    float*    Dmat  = (float*)d_ws;                          // 589824 B
    unsigned* flags = (unsigned*)((char*)d_ws + 589824);     // 96 x 64 B

    triplet_one<<<dim3(NB), dim3(NT), 0, stream>>>(X, labels, Dmat, flags,
                                                   (float*)d_out);
}